// Round 1
// baseline (111.008 us; speedup 1.0000x reference)
//
#include <hip/hip_runtime.h>
#include <math.h>

#define NL    4096      // coarse points
#define NH    16384     // fine points
#define NF4   64        // 256 features / 4
#define BLK   512       // threads per block (8 waves)
#define FPB   64        // fine points per block
#define HALF  2048      // coarse points staged per LDS phase
#define PERW  256       // candidates per wave per half (8 waves * 256 * 2 halves = 4096)

// Strict-< insert (candidates arrive in ascending index order, so strict <
// keeps the earliest (lowest) index on ties — matches jax.lax.top_k stability).
__device__ __forceinline__ void ins3(float d, int j,
    float& b0, float& b1, float& b2, int& i0, int& i1, int& i2)
{
  bool s2 = d < b2;
  b2 = s2 ? d : b2;  i2 = s2 ? j : i2;
  bool s1 = b2 < b1;
  float tf = b1; int ti = i1;
  b1 = s1 ? b2 : b1;  i1 = s1 ? i2 : i1;
  b2 = s1 ? tf : b2;  i2 = s1 ? ti : i2;
  bool s0 = b1 < b0;
  tf = b0; ti = i0;
  b0 = s0 ? b1 : b0;  i0 = s0 ? i1 : i0;
  b1 = s0 ? tf : b1;  i1 = s0 ? ti : i1;
}

// Lexicographic (d, j) insert — used when merging lists whose index order is arbitrary.
__device__ __forceinline__ void lexins3(float d, int j,
    float& b0, float& b1, float& b2, int& i0, int& i1, int& i2)
{
  bool s2 = (d < b2) || ((d == b2) && (j < i2));
  b2 = s2 ? d : b2;  i2 = s2 ? j : i2;
  bool s1 = (b2 < b1) || ((b2 == b1) && (i2 < i1));
  float tf = b1; int ti = i1;
  b1 = s1 ? b2 : b1;  i1 = s1 ? i2 : i1;
  b2 = s1 ? tf : b2;  i2 = s1 ? ti : i2;
  bool s0 = (b1 < b0) || ((b1 == b0) && (i1 < i0));
  tf = b0; ti = i0;
  b0 = s0 ? b1 : b0;  i0 = s0 ? i1 : i0;
  b1 = s0 ? tf : b1;  i1 = s0 ? ti : i1;
}

__global__ __launch_bounds__(BLK)
void knn_interp_kernel(const float* __restrict__ x,
                       const float* __restrict__ pos_l,
                       const float* __restrict__ pos_h,
                       float* __restrict__ out)
{
  __shared__ float4 pl4[HALF];          // staged coarse (x,y,z,|l|^2)   32 KB
  __shared__ float  pd[8 * FPB * 3];    // per-wave partial top-3 dists   6 KB
  __shared__ int    pj[8 * FPB * 3];    // per-wave partial top-3 idx     6 KB
  __shared__ float  wn[FPB * 3];        // normalized weights
  __shared__ int    sj[FPB * 3];        // selected neighbor idx

  const int tid  = threadIdx.x;
  const int lane = tid & 63;
  const int wv   = __builtin_amdgcn_readfirstlane(tid >> 6);   // wave id 0..7, uniform
  const int fg   = blockIdx.x * FPB + lane;                    // fine point for this thread

  // fine position + |h|^2 with np rounding: (h0^2 + h1^2) + h2^2, no fma contraction
  const float h0 = pos_h[fg * 3 + 0];
  const float h1 = pos_h[fg * 3 + 1];
  const float h2 = pos_h[fg * 3 + 2];
  const float hh = __fadd_rn(__fadd_rn(__fmul_rn(h0, h0), __fmul_rn(h1, h1)),
                             __fmul_rn(h2, h2));

  // two independent top-3 accumulator sets (even / odd candidates) for ILP
  float a0 = INFINITY, a1 = INFINITY, a2 = INFINITY;  int ai0 = 0, ai1 = 0, ai2 = 0;
  float c0 = INFINITY, c1 = INFINITY, c2 = INFINITY;  int ci0 = 0, ci1 = 0, ci2 = 0;

  for (int half = 0; half < 2; ++half) {
    // stage HALF coarse points into LDS, precompute |l|^2 with np rounding
    for (int p = tid; p < HALF; p += BLK) {
      const int g = half * HALF + p;
      const float l0 = pos_l[g * 3 + 0];
      const float l1 = pos_l[g * 3 + 1];
      const float l2 = pos_l[g * 3 + 2];
      const float ll = __fadd_rn(__fadd_rn(__fmul_rn(l0, l0), __fmul_rn(l1, l1)),
                                 __fmul_rn(l2, l2));
      pl4[p] = make_float4(l0, l1, l2, ll);
    }
    __syncthreads();

    const int base  = wv * PERW;          // wave's slice within the staged half
    const int jbase = half * HALF + base; // global coarse index of slice start

    #pragma unroll 4
    for (int t = 0; t < PERW; t += 2) {
      const float4 pa = pl4[base + t];
      const float4 pb = pl4[base + t + 1];
      // d2 = (hh - 2*dot) + ll, dot = fma ascending chain — matches np/BLAS rounding
      const float dota = __fmaf_rn(h2, pa.z, __fmaf_rn(h1, pa.y, __fmul_rn(h0, pa.x)));
      const float da   = __fadd_rn(__fsub_rn(hh, __fmul_rn(2.0f, dota)), pa.w);
      const float dotb = __fmaf_rn(h2, pb.z, __fmaf_rn(h1, pb.y, __fmul_rn(h0, pb.x)));
      const float db   = __fadd_rn(__fsub_rn(hh, __fmul_rn(2.0f, dotb)), pb.w);
      ins3(da, jbase + t,     a0, a1, a2, ai0, ai1, ai2);
      ins3(db, jbase + t + 1, c0, c1, c2, ci0, ci1, ci2);
    }
    __syncthreads();   // before re-staging / before merge phase
  }

  // merge odd-set into even-set (index order arbitrary between sets -> lex)
  lexins3(c0, ci0, a0, a1, a2, ai0, ai1, ai2);
  lexins3(c1, ci1, a0, a1, a2, ai0, ai1, ai2);
  lexins3(c2, ci2, a0, a1, a2, ai0, ai1, ai2);

  {
    const int s = (wv * FPB + lane) * 3;
    pd[s + 0] = a0; pd[s + 1] = a1; pd[s + 2] = a2;
    pj[s + 0] = ai0; pj[s + 1] = ai1; pj[s + 2] = ai2;
  }
  __syncthreads();

  // wave 0: merge 8 partial lists per fine point, compute exact weights
  if (tid < FPB) {
    float b0 = INFINITY, b1 = INFINITY, b2 = INFINITY;
    int   i0 = 0x7fffffff, i1 = 0x7fffffff, i2 = 0x7fffffff;
    for (int w = 0; w < 8; ++w) {
      const int s = (w * FPB + tid) * 3;
      lexins3(pd[s + 0], pj[s + 0], b0, b1, b2, i0, i1, i2);
      lexins3(pd[s + 1], pj[s + 1], b0, b1, b2, i0, i1, i2);
      lexins3(pd[s + 2], pj[s + 2], b0, b1, b2, i0, i1, i2);
    }

    const int fm = blockIdx.x * FPB + tid;
    const float H0 = pos_h[fm * 3 + 0];
    const float H1 = pos_h[fm * 3 + 1];
    const float H2 = pos_h[fm * 3 + 2];

    float wk[3];
    int   jk[3] = { i0, i1, i2 };
    #pragma unroll
    for (int k = 0; k < 3; ++k) {
      const int j = jk[k];
      // exact recompute per reference: diff, squares, sequential sum (no fma)
      const float dx = __fsub_rn(H0, pos_l[j * 3 + 0]);
      const float dy = __fsub_rn(H1, pos_l[j * 3 + 1]);
      const float dz = __fsub_rn(H2, pos_l[j * 3 + 2]);
      float d2 = __fadd_rn(__fadd_rn(__fmul_rn(dx, dx), __fmul_rn(dy, dy)),
                           __fmul_rn(dz, dz));
      d2 = fmaxf(d2, 1e-16f);              // clip(d2, EPS)
      wk[k] = __frcp_rn(d2);               // correctly-rounded 1/d2 (matches np divide)
    }
    const float W  = __fadd_rn(__fadd_rn(wk[0], wk[1]), wk[2]);
    const float rW = __frcp_rn(W);
    #pragma unroll
    for (int k = 0; k < 3; ++k) {
      wn[tid * 3 + k] = wk[k] * rW;        // pre-normalized weights (~1 ulp vs S/W, fine)
      sj[tid * 3 + k] = jk[k];
    }
  }
  __syncthreads();

  // interpolation: 64 fine x 64 float4 = 4096 tasks per block, 8 per thread
  const float4* __restrict__ x4   = (const float4*)x;
  float4* __restrict__       out4 = (float4*)out;
  #pragma unroll
  for (int i = 0; i < (FPB * NF4) / BLK; ++i) {
    const int task = tid + i * BLK;
    const int f    = task >> 6;         // local fine point
    const int cc   = task & 63;         // float4 column
    const int j0 = sj[f * 3 + 0], j1 = sj[f * 3 + 1], j2 = sj[f * 3 + 2];
    const float w0 = wn[f * 3 + 0], w1 = wn[f * 3 + 1], w2 = wn[f * 3 + 2];
    const float4 xa = x4[j0 * NF4 + cc];
    const float4 xb = x4[j1 * NF4 + cc];
    const float4 xc = x4[j2 * NF4 + cc];
    float4 r;
    r.x = xa.x * w0 + xb.x * w1 + xc.x * w2;
    r.y = xa.y * w0 + xb.y * w1 + xc.y * w2;
    r.z = xa.z * w0 + xb.z * w1 + xc.z * w2;
    r.w = xa.w * w0 + xb.w * w1 + xc.w * w2;
    out4[(blockIdx.x * FPB + f) * NF4 + cc] = r;
  }
}

extern "C" void kernel_launch(void* const* d_in, const int* in_sizes, int n_in,
                              void* d_out, int out_size, void* d_ws, size_t ws_size,
                              hipStream_t stream)
{
  const float* x     = (const float*)d_in[0];   // [4096, 256]
  const float* pos_l = (const float*)d_in[1];   // [4096, 3]
  const float* pos_h = (const float*)d_in[2];   // [16384, 3]
  float* out = (float*)d_out;                   // [16384, 256]

  dim3 grid(NH / FPB);   // 256 blocks
  dim3 block(BLK);       // 512 threads (8 waves)
  hipLaunchKernelGGL(knn_interp_kernel, grid, block, 0, stream, x, pos_l, pos_h, out);
}